// Round 8
// baseline (345.909 us; speedup 1.0000x reference)
//
#include <hip/hip_runtime.h>

#define NN 50000
#define NE 1600000
#define NB 391        // coarse buckets of 128 nodes
#define NBLK 128      // blocks in P1/P3 (12500 edges each)
#define NSEG 50048    // NB*128 scan entries

typedef short bf16x8 __attribute__((ext_vector_type(8)));
typedef float f32x4 __attribute__((ext_vector_type(4)));

static __device__ __forceinline__ unsigned f2bf(float f) {
    union { float f; unsigned u; } v; v.f = f;
    return (v.u + 0x7FFF + ((v.u >> 16) & 1)) >> 16;   // RNE
}

// P1: per-block LDS histogram over 391 coarse buckets
__global__ __launch_bounds__(256) void p1_hist(const int* __restrict__ dst,
        int* __restrict__ cntB) {
    __shared__ int h[NB];
    for (int i = threadIdx.x; i < NB; i += 256) h[i] = 0;
    __syncthreads();
    int base = blockIdx.x * 12500;
    for (int k = threadIdx.x; k < 12500; k += 256)
        atomicAdd(&h[dst[base + k] >> 7], 1);
    __syncthreads();
    for (int i = threadIdx.x; i < NB; i += 256)
        cntB[i * NBLK + blockIdx.x] = h[i];
}

// scan chain over NSEG entries: csum = exclusive scan of cntB, csum[NSEG]=NE
__global__ __launch_bounds__(256) void scan1_kernel(const int* __restrict__ in,
        int* __restrict__ csum, int* __restrict__ bsum) {
    __shared__ int sd[256];
    int t = threadIdx.x;
    int idx = blockIdx.x * 256 + t;
    int v = (idx < NSEG) ? in[idx] : 0;
    sd[t] = v;
    __syncthreads();
    for (int off = 1; off < 256; off <<= 1) {
        int x = (t >= off) ? sd[t - off] : 0;
        __syncthreads();
        sd[t] += x;
        __syncthreads();
    }
    if (idx < NSEG) csum[idx + 1] = sd[t];
    if (t == 255) bsum[blockIdx.x] = sd[255];
}

__global__ __launch_bounds__(256) void scan2_kernel(int* __restrict__ bsum,
        int* __restrict__ csum) {
    __shared__ int sd[256];
    int t = threadIdx.x;
    int v = (t < 196) ? bsum[t] : 0;
    sd[t] = v;
    __syncthreads();
    for (int off = 1; off < 256; off <<= 1) {
        int x = (t >= off) ? sd[t - off] : 0;
        __syncthreads();
        sd[t] += x;
        __syncthreads();
    }
    if (t < 196) bsum[t] = sd[t] - v;
    if (t == 0) csum[0] = 0;
}

__global__ __launch_bounds__(256) void scan3_kernel(int* __restrict__ csum,
        const int* __restrict__ bsum) {
    int idx = blockIdx.x * 256 + threadIdx.x;
    if (idx < NSEG) csum[idx + 1] += bsum[blockIdx.x];
}

// P3: bucket-order scatter; slots per (bucket,block) are disjoint via csum
__global__ __launch_bounds__(256) void p3_scatter(const int* __restrict__ src,
        const int* __restrict__ dst, const float* __restrict__ ew,
        const int* __restrict__ csum, int2* __restrict__ ebuf) {
    __shared__ int curs[NB];
    for (int i = threadIdx.x; i < NB; i += 256)
        curs[i] = csum[i * NBLK + blockIdx.x];
    __syncthreads();
    int base = blockIdx.x * 12500;
    for (int k = threadIdx.x; k < 12500; k += 256) {
        int d = dst[base + k];
        int s = src[base + k];
        float w = ew[base + k];
        int pos = atomicAdd(&curs[d >> 7], 1);
        ebuf[pos] = make_int2(s | ((d & 127) << 16), __float_as_int(w));
    }
}

// P4: one block per bucket — local count + weighted degree + scan + place.
// Emits rowptr, dinv, and dst-sorted edata = {src, bits(ew)}.
__global__ __launch_bounds__(256) void p4_build(const int2* __restrict__ ebuf,
        const int* __restrict__ csum, int2* __restrict__ edata,
        float* __restrict__ dinv, int* __restrict__ rowptr) {
    __shared__ int cnt[128], loff[128], cur[128], sd[128];
    __shared__ float deg[128];
    int bk = blockIdx.x;
    int t = threadIdx.x;
    int ebase = csum[bk * 128];
    int ecnt = csum[(bk + 1) * 128] - ebase;
    if (t < 128) { cnt[t] = 0; cur[t] = 0; deg[t] = 0.0f; }
    __syncthreads();
    for (int i = t; i < ecnt; i += 256) {
        int2 e = ebuf[ebase + i];
        int dl = (e.x >> 16) & 127;
        atomicAdd(&cnt[dl], 1);
        atomicAdd(&deg[dl], __int_as_float(e.y));
    }
    __syncthreads();
    if (t < 128) sd[t] = cnt[t];
    __syncthreads();
    for (int off = 1; off < 128; off <<= 1) {
        int v = 0;
        if (t < 128 && t >= off) v = sd[t - off];
        __syncthreads();
        if (t < 128) sd[t] += v;
        __syncthreads();
    }
    if (t < 128) loff[t] = sd[t] - cnt[t];
    __syncthreads();
    int node = bk * 128 + t;
    if (t < 128 && node < NN) {
        dinv[node] = rsqrtf(deg[t] + 1.0f);
        rowptr[node] = ebase + loff[t];
    }
    if (bk == NB - 1 && t == 0) rowptr[NN] = NE;
    for (int i = t; i < ecnt; i += 256) {
        int2 e = ebuf[ebase + i];
        int dl = (e.x >> 16) & 127;
        int slot = loff[dl] + atomicAdd(&cur[dl], 1);
        edata[ebase + slot] = make_int2(e.x & 0xFFFF, e.y);
    }
}

// Wt1[n*256+k]=bf16(W1[k*128+n]); Wt2[n*128+k]=bf16(W2[k*64+n]) — one launch
__global__ __launch_bounds__(256) void wt_kernel(const float* __restrict__ W1,
        const float* __restrict__ W2, ushort* __restrict__ Wt1,
        ushort* __restrict__ Wt2) {
    int idx = blockIdx.x * 256 + threadIdx.x;
    if (idx < 32768) {
        int k = idx >> 7, n = idx & 127;
        Wt1[n * 256 + k] = (ushort)f2bf(W1[idx]);
    } else if (idx < 40960) {
        int i = idx - 32768;
        int k = i >> 6, n = i & 63;
        Wt2[n * 128 + k] = (ushort)f2bf(W2[i]);
    }
}

// C chunked: C[((col>>5)*NN + row)*32 + (col&31)] = dinv[row] * (A x Bt)
// A fp32 [M,K]; Bt bf16 [n][k]. fp32 acc. K%64==0, N%64==0.
__global__ __launch_bounds__(256) void gemm_a32_kernel(const float* __restrict__ A,
        const ushort* __restrict__ Bt, ushort* __restrict__ C,
        const float* __restrict__ dinv, int M, int N, int K) {
    __shared__ __align__(16) ushort As[64][72];
    __shared__ __align__(16) ushort Bs[64][72];
    int tid = threadIdx.x;
    int bm = blockIdx.y * 64, bn = blockIdx.x * 64;
    int w = tid >> 6, lane = tid & 63;
    int m = lane & 15, quad = lane >> 4;
    f32x4 acc[4] = {};
    int r = tid >> 2, ks0 = (tid & 3) * 16;
    int grow = bm + r; if (grow >= M) grow = M - 1;
    const float* ap = A + (size_t)grow * K + ks0;
    const ushort* bp = Bt + (size_t)(bn + r) * K + ks0;
    for (int k0 = 0; k0 < K; k0 += 64) {
        float4 f0 = *(const float4*)(ap + k0);
        float4 f1 = *(const float4*)(ap + k0 + 4);
        float4 f2 = *(const float4*)(ap + k0 + 8);
        float4 f3 = *(const float4*)(ap + k0 + 12);
        uint4 bv0 = *(const uint4*)(bp + k0);
        uint4 bv1 = *(const uint4*)(bp + k0 + 8);
        uint4 pa, pb;
        pa.x = f2bf(f0.x) | (f2bf(f0.y) << 16);
        pa.y = f2bf(f0.z) | (f2bf(f0.w) << 16);
        pa.z = f2bf(f1.x) | (f2bf(f1.y) << 16);
        pa.w = f2bf(f1.z) | (f2bf(f1.w) << 16);
        pb.x = f2bf(f2.x) | (f2bf(f2.y) << 16);
        pb.y = f2bf(f2.z) | (f2bf(f2.w) << 16);
        pb.z = f2bf(f3.x) | (f2bf(f3.y) << 16);
        pb.w = f2bf(f3.z) | (f2bf(f3.w) << 16);
        __syncthreads();
        *(uint4*)&As[r][ks0] = pa;
        *(uint4*)&As[r][ks0 + 8] = pb;
        *(uint4*)&Bs[r][ks0] = bv0;
        *(uint4*)&Bs[r][ks0 + 8] = bv1;
        __syncthreads();
        #pragma unroll
        for (int ks = 0; ks < 2; ++ks) {
            bf16x8 a = *(const bf16x8*)&As[w * 16 + m][ks * 32 + quad * 8];
            #pragma unroll
            for (int t = 0; t < 4; ++t) {
                bf16x8 b = *(const bf16x8*)&Bs[t * 16 + m][ks * 32 + quad * 8];
                acc[t] = __builtin_amdgcn_mfma_f32_16x16x32_bf16(a, b, acc[t], 0, 0, 0);
            }
        }
    }
    int rbase = bm + w * 16 + quad * 4;
    float dv[4];
    #pragma unroll
    for (int rg = 0; rg < 4; ++rg)
        dv[rg] = (rbase + rg < M) ? dinv[rbase + rg] : 0.0f;
    #pragma unroll
    for (int t = 0; t < 4; ++t) {
        int col = bn + t * 16 + m;
        int q = col >> 5, cw = col & 31;
        #pragma unroll
        for (int rg = 0; rg < 4; ++rg) {
            int row = rbase + rg;
            if (row < M)
                C[((size_t)q * NN + row) * 32 + cw] = (ushort)f2bf(dv[rg] * acc[t][rg]);
        }
    }
}

// Same, A bf16 row-major [M,K].
__global__ __launch_bounds__(256) void gemm_a16_kernel(const ushort* __restrict__ A,
        const ushort* __restrict__ Bt, ushort* __restrict__ C,
        const float* __restrict__ dinv, int M, int N, int K) {
    __shared__ __align__(16) ushort As[64][72];
    __shared__ __align__(16) ushort Bs[64][72];
    int tid = threadIdx.x;
    int bm = blockIdx.y * 64, bn = blockIdx.x * 64;
    int w = tid >> 6, lane = tid & 63;
    int m = lane & 15, quad = lane >> 4;
    f32x4 acc[4] = {};
    int r = tid >> 2, ks0 = (tid & 3) * 16;
    int grow = bm + r; if (grow >= M) grow = M - 1;
    const ushort* ap = A + (size_t)grow * K + ks0;
    const ushort* bp = Bt + (size_t)(bn + r) * K + ks0;
    for (int k0 = 0; k0 < K; k0 += 64) {
        uint4 av0 = *(const uint4*)(ap + k0);
        uint4 av1 = *(const uint4*)(ap + k0 + 8);
        uint4 bv0 = *(const uint4*)(bp + k0);
        uint4 bv1 = *(const uint4*)(bp + k0 + 8);
        __syncthreads();
        *(uint4*)&As[r][ks0] = av0;
        *(uint4*)&As[r][ks0 + 8] = av1;
        *(uint4*)&Bs[r][ks0] = bv0;
        *(uint4*)&Bs[r][ks0 + 8] = bv1;
        __syncthreads();
        #pragma unroll
        for (int ks = 0; ks < 2; ++ks) {
            bf16x8 a = *(const bf16x8*)&As[w * 16 + m][ks * 32 + quad * 8];
            #pragma unroll
            for (int t = 0; t < 4; ++t) {
                bf16x8 b = *(const bf16x8*)&Bs[t * 16 + m][ks * 32 + quad * 8];
                acc[t] = __builtin_amdgcn_mfma_f32_16x16x32_bf16(a, b, acc[t], 0, 0, 0);
            }
        }
    }
    int rbase = bm + w * 16 + quad * 4;
    float dv[4];
    #pragma unroll
    for (int rg = 0; rg < 4; ++rg)
        dv[rg] = (rbase + rg < M) ? dinv[rbase + rg] : 0.0f;
    #pragma unroll
    for (int t = 0; t < 4; ++t) {
        int col = bn + t * 16 + m;
        int q = col >> 5, cw = col & 31;
        #pragma unroll
        for (int rg = 0; rg < 4; ++rg) {
            int row = rbase + rg;
            if (row < M)
                C[((size_t)q * NN + row) * 32 + cw] = (ushort)f2bf(dv[rg] * acc[t][rg]);
        }
    }
}

// Chunked aggregation: blockIdx.y = 32-feature chunk; chunk table = 3.2 MB
// (fits one XCD L2). 4 lanes per node, 16 B each. H pre-scaled by dinv[row]:
// out[n,chunk] = dinv[n]*(sum_j ew_j*Hc[s_j] + Hc[n]) + bias_c  (opt relu)
template<int RELU, int OUTBF>
__global__ __launch_bounds__(256) void agg_chunk_kernel(
        const int* __restrict__ rowptr, const int2* __restrict__ edata,
        const ushort* __restrict__ Htab, const float* __restrict__ dinv,
        const float* __restrict__ bias, void* __restrict__ outv, int ostride) {
    int chunk = blockIdx.y;
    const ushort* Hc = Htab + (size_t)chunk * NN * 32;
    int node = blockIdx.x * 64 + (threadIdx.x >> 2);
    if (node >= NN) return;
    int glane = threadIdx.x & 3;
    int gb = (threadIdx.x & 63) & ~3;   // group base lane within wave
    int beg = rowptr[node], end = rowptr[node + 1];
    float acc[8] = {};
    const ushort* Hl = Hc + glane * 8;
    for (int c0 = beg; c0 < end; c0 += 4) {
        int nch = end - c0; if (nch > 4) nch = 4;
        int edx = 0, edy = 0;
        if (glane < nch) {
            int2 e = edata[c0 + glane];
            edx = e.x; edy = e.y;
        }
        int j = 0;
        for (; j + 2 <= nch; j += 2) {
            int s0 = __shfl(edx, gb + j);
            int s1 = __shfl(edx, gb + j + 1);
            float c0f = __int_as_float(__shfl(edy, gb + j));
            float c1f = __int_as_float(__shfl(edy, gb + j + 1));
            uint4 h0 = *(const uint4*)(Hl + (size_t)s0 * 32);
            uint4 h1 = *(const uint4*)(Hl + (size_t)s1 * 32);
            const unsigned* u0 = (const unsigned*)&h0;
            const unsigned* u1 = (const unsigned*)&h1;
            #pragma unroll
            for (int q = 0; q < 4; ++q) {
                acc[2*q]   += __uint_as_float(u0[q] << 16) * c0f;
                acc[2*q+1] += __uint_as_float(u0[q] & 0xFFFF0000u) * c0f;
            }
            #pragma unroll
            for (int q = 0; q < 4; ++q) {
                acc[2*q]   += __uint_as_float(u1[q] << 16) * c1f;
                acc[2*q+1] += __uint_as_float(u1[q] & 0xFFFF0000u) * c1f;
            }
        }
        if (j < nch) {
            int s0 = __shfl(edx, gb + j);
            float c0f = __int_as_float(__shfl(edy, gb + j));
            uint4 h0 = *(const uint4*)(Hl + (size_t)s0 * 32);
            const unsigned* u0 = (const unsigned*)&h0;
            #pragma unroll
            for (int q = 0; q < 4; ++q) {
                acc[2*q]   += __uint_as_float(u0[q] << 16) * c0f;
                acc[2*q+1] += __uint_as_float(u0[q] & 0xFFFF0000u) * c0f;
            }
        }
    }
    float di = dinv[node];
    uint4 hn = *(const uint4*)(Hl + (size_t)node * 32);
    const unsigned* un = (const unsigned*)&hn;
    const float* bc = bias + chunk * 32 + glane * 8;
    float4 bv0 = *(const float4*)(bc);
    float4 bv1 = *(const float4*)(bc + 4);
    float v[8];
    #pragma unroll
    for (int q = 0; q < 4; ++q) {
        v[2*q]   = di * (acc[2*q]   + __uint_as_float(un[q] << 16));
        v[2*q+1] = di * (acc[2*q+1] + __uint_as_float(un[q] & 0xFFFF0000u));
    }
    v[0] += bv0.x; v[1] += bv0.y; v[2] += bv0.z; v[3] += bv0.w;
    v[4] += bv1.x; v[5] += bv1.y; v[6] += bv1.z; v[7] += bv1.w;
    if (RELU) {
        #pragma unroll
        for (int k = 0; k < 8; ++k) v[k] = fmaxf(v[k], 0.0f);
    }
    if (OUTBF) {
        uint4 o;
        o.x = f2bf(v[0]) | (f2bf(v[1]) << 16);
        o.y = f2bf(v[2]) | (f2bf(v[3]) << 16);
        o.z = f2bf(v[4]) | (f2bf(v[5]) << 16);
        o.w = f2bf(v[6]) | (f2bf(v[7]) << 16);
        *(uint4*)((ushort*)outv + (size_t)node * ostride + chunk * 32 + glane * 8) = o;
    } else {
        float* o = (float*)outv + (size_t)node * ostride + chunk * 32 + glane * 8;
        *(float4*)(o)     = make_float4(v[0], v[1], v[2], v[3]);
        *(float4*)(o + 4) = make_float4(v[4], v[5], v[6], v[7]);
    }
}

extern "C" void kernel_launch(void* const* d_in, const int* in_sizes, int n_in,
                              void* d_out, int out_size, void* d_ws, size_t ws_size,
                              hipStream_t stream) {
    const float* x  = (const float*)d_in[0];
    const int*   ei = (const int*)d_in[1];
    const float* ew = (const float*)d_in[2];
    const float* W1 = (const float*)d_in[3];
    const float* b1 = (const float*)d_in[4];
    const float* W2 = (const float*)d_in[5];
    const float* b2 = (const float*)d_in[6];
    const int* src = ei;
    const int* dst = ei + NE;
    float* out = (float*)d_out;

    // workspace (dword offsets):
    float* ws     = (float*)d_ws;
    float* dinv   = ws;                        // 50048 dw
    int*   rowptr = (int*)(ws + 50048);        // 50064 dw (NN+1)
    int*   csum   = (int*)(ws + 100112);       // 50064 dw (NSEG+1)
    int*   bsum   = (int*)(ws + 150176);       // 352 dw
    int*   cntB   = (int*)(ws + 150528);       // 50048 dw
    ushort* Wt1   = (ushort*)(ws + 200576);    // 16384 dw
    ushort* Wt2   = Wt1 + 32768;               // 4096 dw -> ends 221056
    int2*  edata  = (int2*)(ws + 221056);      // 3.2M dw
    ushort* H1    = (ushort*)(ws + 3421056);   // chunked [4][NN][32] bf16 (H2: [2][NN][32])
    ushort* A1    = (ushort*)(ws + 6621056);   // row-major [NN][128] bf16
    int2*  ebuf   = (int2*)A1;                 // aliases A1 (dead before agg1 writes)
    // total 9,821,056 dw = 39.3 MB

    // CSR build: zero global atomics (LDS counting sort, 2 levels)
    p1_hist<<<NBLK, 256, 0, stream>>>(dst, cntB);
    scan1_kernel<<<196, 256, 0, stream>>>(cntB, csum, bsum);
    scan2_kernel<<<1, 256, 0, stream>>>(bsum, csum);
    scan3_kernel<<<196, 256, 0, stream>>>(csum, bsum);
    wt_kernel<<<160, 256, 0, stream>>>(W1, W2, Wt1, Wt2);
    p3_scatter<<<NBLK, 256, 0, stream>>>(src, dst, ew, csum, ebuf);
    p4_build<<<NB, 256, 0, stream>>>(ebuf, csum, edata, dinv, rowptr);

    // Layer 1: H1'(chunked bf16) = dinv*(x @ W1) -> agg (4 chunks) -> A1(relu)
    gemm_a32_kernel<<<dim3(2, 782), 256, 0, stream>>>(x, Wt1, H1, dinv, NN, 128, 256);
    agg_chunk_kernel<1, 1><<<dim3(782, 4), 256, 0, stream>>>(
        rowptr, edata, H1, dinv, b1, A1, 128);

    // Layer 2: H2'(chunked bf16) = dinv*(A1 @ W2) -> agg (2 chunks) -> out(fp32)
    gemm_a16_kernel<<<dim3(1, 782), 256, 0, stream>>>(A1, Wt2, H1, dinv, NN, 64, 128);
    agg_chunk_kernel<0, 0><<<dim3(782, 2), 256, 0, stream>>>(
        rowptr, edata, H1, dinv, b2, out, 64);
}

// Round 9
// 266.136 us; speedup vs baseline: 1.2997x; 1.2997x over previous
//
#include <hip/hip_runtime.h>

#define NN 50000
#define NE 1600000
#define NB 391        // coarse buckets of 128 nodes
#define NBLK 128      // blocks in P1/P3 (12500 edges each)
#define NSEG 50048    // NB*128 scan entries

typedef short bf16x8 __attribute__((ext_vector_type(8)));
typedef float f32x4 __attribute__((ext_vector_type(4)));

static __device__ __forceinline__ unsigned f2bf(float f) {
    union { float f; unsigned u; } v; v.f = f;
    return (v.u + 0x7FFF + ((v.u >> 16) & 1)) >> 16;   // RNE
}

// P1: per-block LDS histogram over 391 coarse buckets
__global__ __launch_bounds__(256) void p1_hist(const int* __restrict__ dst,
        int* __restrict__ cntB) {
    __shared__ int h[NB];
    for (int i = threadIdx.x; i < NB; i += 256) h[i] = 0;
    __syncthreads();
    int base = blockIdx.x * 12500;
    for (int k = threadIdx.x; k < 12500; k += 256)
        atomicAdd(&h[dst[base + k] >> 7], 1);
    __syncthreads();
    for (int i = threadIdx.x; i < NB; i += 256)
        cntB[i * NBLK + blockIdx.x] = h[i];
}

// scan chain over NSEG entries: csum = exclusive scan of cntB, csum[NSEG]=NE
__global__ __launch_bounds__(256) void scan1_kernel(const int* __restrict__ in,
        int* __restrict__ csum, int* __restrict__ bsum) {
    __shared__ int sd[256];
    int t = threadIdx.x;
    int idx = blockIdx.x * 256 + t;
    int v = (idx < NSEG) ? in[idx] : 0;
    sd[t] = v;
    __syncthreads();
    for (int off = 1; off < 256; off <<= 1) {
        int x = (t >= off) ? sd[t - off] : 0;
        __syncthreads();
        sd[t] += x;
        __syncthreads();
    }
    if (idx < NSEG) csum[idx + 1] = sd[t];
    if (t == 255) bsum[blockIdx.x] = sd[255];
}

__global__ __launch_bounds__(256) void scan2_kernel(int* __restrict__ bsum,
        int* __restrict__ csum) {
    __shared__ int sd[256];
    int t = threadIdx.x;
    int v = (t < 196) ? bsum[t] : 0;
    sd[t] = v;
    __syncthreads();
    for (int off = 1; off < 256; off <<= 1) {
        int x = (t >= off) ? sd[t - off] : 0;
        __syncthreads();
        sd[t] += x;
        __syncthreads();
    }
    if (t < 196) bsum[t] = sd[t] - v;
    if (t == 0) csum[0] = 0;
}

__global__ __launch_bounds__(256) void scan3_kernel(int* __restrict__ csum,
        const int* __restrict__ bsum) {
    int idx = blockIdx.x * 256 + threadIdx.x;
    if (idx < NSEG) csum[idx + 1] += bsum[blockIdx.x];
}

// P3: bucket-order scatter; slots per (bucket,block) are disjoint via csum
__global__ __launch_bounds__(256) void p3_scatter(const int* __restrict__ src,
        const int* __restrict__ dst, const float* __restrict__ ew,
        const int* __restrict__ csum, int2* __restrict__ ebuf) {
    __shared__ int curs[NB];
    for (int i = threadIdx.x; i < NB; i += 256)
        curs[i] = csum[i * NBLK + blockIdx.x];
    __syncthreads();
    int base = blockIdx.x * 12500;
    for (int k = threadIdx.x; k < 12500; k += 256) {
        int d = dst[base + k];
        int s = src[base + k];
        float w = ew[base + k];
        int pos = atomicAdd(&curs[d >> 7], 1);
        ebuf[pos] = make_int2(s | ((d & 127) << 16), __float_as_int(w));
    }
}

// P4: one block per bucket — local count + weighted degree + scan + place.
// Emits rowptr, dinv, and dst-sorted edata = {src, bits(ew)}.
__global__ __launch_bounds__(256) void p4_build(const int2* __restrict__ ebuf,
        const int* __restrict__ csum, int2* __restrict__ edata,
        float* __restrict__ dinv, int* __restrict__ rowptr) {
    __shared__ int cnt[128], loff[128], cur[128], sd[128];
    __shared__ float deg[128];
    int bk = blockIdx.x;
    int t = threadIdx.x;
    int ebase = csum[bk * 128];
    int ecnt = csum[(bk + 1) * 128] - ebase;
    if (t < 128) { cnt[t] = 0; cur[t] = 0; deg[t] = 0.0f; }
    __syncthreads();
    for (int i = t; i < ecnt; i += 256) {
        int2 e = ebuf[ebase + i];
        int dl = (e.x >> 16) & 127;
        atomicAdd(&cnt[dl], 1);
        atomicAdd(&deg[dl], __int_as_float(e.y));
    }
    __syncthreads();
    if (t < 128) sd[t] = cnt[t];
    __syncthreads();
    for (int off = 1; off < 128; off <<= 1) {
        int v = 0;
        if (t < 128 && t >= off) v = sd[t - off];
        __syncthreads();
        if (t < 128) sd[t] += v;
        __syncthreads();
    }
    if (t < 128) loff[t] = sd[t] - cnt[t];
    __syncthreads();
    int node = bk * 128 + t;
    if (t < 128 && node < NN) {
        dinv[node] = rsqrtf(deg[t] + 1.0f);
        rowptr[node] = ebase + loff[t];
    }
    if (bk == NB - 1 && t == 0) rowptr[NN] = NE;
    for (int i = t; i < ecnt; i += 256) {
        int2 e = ebuf[ebase + i];
        int dl = (e.x >> 16) & 127;
        int slot = loff[dl] + atomicAdd(&cur[dl], 1);
        edata[ebase + slot] = make_int2(e.x & 0xFFFF, e.y);
    }
}

// Wt1[n*256+k]=bf16(W1[k*128+n]); Wt2[n*128+k]=bf16(W2[k*64+n]) — one launch
__global__ __launch_bounds__(256) void wt_kernel(const float* __restrict__ W1,
        const float* __restrict__ W2, ushort* __restrict__ Wt1,
        ushort* __restrict__ Wt2) {
    int idx = blockIdx.x * 256 + threadIdx.x;
    if (idx < 32768) {
        int k = idx >> 7, n = idx & 127;
        Wt1[n * 256 + k] = (ushort)f2bf(W1[idx]);
    } else if (idx < 40960) {
        int i = idx - 32768;
        int k = i >> 6, n = i & 63;
        Wt2[n * 128 + k] = (ushort)f2bf(W2[i]);
    }
}

// Layer-1 GEMM: C[M,128](bf16,row-major) = dinv[row]*(A[M,256](fp32) x Bt[128][256](bf16))
// Tile 64x128 (full N) so A is read exactly once. 4 waves; each wave 16 rows.
__global__ __launch_bounds__(256) void gemm1_kernel(const float* __restrict__ A,
        const ushort* __restrict__ Bt, ushort* __restrict__ C,
        const float* __restrict__ dinv, int M) {
    const int K = 256, N = 128;
    __shared__ __align__(16) ushort As[64][72];
    __shared__ __align__(16) ushort Bs[128][72];
    int tid = threadIdx.x;
    int bm = blockIdx.x * 64;
    int w = tid >> 6, lane = tid & 63;
    int m = lane & 15, quad = lane >> 4;
    f32x4 acc[8] = {};
    int ra = tid >> 2, ksa = (tid & 3) * 16;        // A staging: 64 rows x 64 k
    int rb = tid >> 1, ksb = (tid & 1) * 32;        // B staging: 128 rows x 64 k
    int grow = bm + ra; if (grow >= M) grow = M - 1;
    const float* ap = A + (size_t)grow * K + ksa;
    const ushort* bp = Bt + (size_t)rb * K + ksb;
    for (int k0 = 0; k0 < K; k0 += 64) {
        float4 f0 = *(const float4*)(ap + k0);
        float4 f1 = *(const float4*)(ap + k0 + 4);
        float4 f2 = *(const float4*)(ap + k0 + 8);
        float4 f3 = *(const float4*)(ap + k0 + 12);
        uint4 bv0 = *(const uint4*)(bp + k0);
        uint4 bv1 = *(const uint4*)(bp + k0 + 8);
        uint4 bv2 = *(const uint4*)(bp + k0 + 16);
        uint4 bv3 = *(const uint4*)(bp + k0 + 24);
        uint4 pa, pb;
        pa.x = f2bf(f0.x) | (f2bf(f0.y) << 16);
        pa.y = f2bf(f0.z) | (f2bf(f0.w) << 16);
        pa.z = f2bf(f1.x) | (f2bf(f1.y) << 16);
        pa.w = f2bf(f1.z) | (f2bf(f1.w) << 16);
        pb.x = f2bf(f2.x) | (f2bf(f2.y) << 16);
        pb.y = f2bf(f2.z) | (f2bf(f2.w) << 16);
        pb.z = f2bf(f3.x) | (f2bf(f3.y) << 16);
        pb.w = f2bf(f3.z) | (f2bf(f3.w) << 16);
        __syncthreads();
        *(uint4*)&As[ra][ksa] = pa;
        *(uint4*)&As[ra][ksa + 8] = pb;
        *(uint4*)&Bs[rb][ksb] = bv0;
        *(uint4*)&Bs[rb][ksb + 8] = bv1;
        *(uint4*)&Bs[rb][ksb + 16] = bv2;
        *(uint4*)&Bs[rb][ksb + 24] = bv3;
        __syncthreads();
        #pragma unroll
        for (int ks = 0; ks < 2; ++ks) {
            bf16x8 a = *(const bf16x8*)&As[w * 16 + m][ks * 32 + quad * 8];
            #pragma unroll
            for (int t = 0; t < 8; ++t) {
                bf16x8 b = *(const bf16x8*)&Bs[t * 16 + m][ks * 32 + quad * 8];
                acc[t] = __builtin_amdgcn_mfma_f32_16x16x32_bf16(a, b, acc[t], 0, 0, 0);
            }
        }
    }
    int rbase = bm + w * 16 + quad * 4;
    float dv[4];
    #pragma unroll
    for (int rg = 0; rg < 4; ++rg)
        dv[rg] = (rbase + rg < M) ? dinv[rbase + rg] : 0.0f;
    #pragma unroll
    for (int t = 0; t < 8; ++t) {
        int col = t * 16 + m;
        #pragma unroll
        for (int rg = 0; rg < 4; ++rg) {
            int row = rbase + rg;
            if (row < M)
                C[(size_t)row * N + col] = (ushort)f2bf(dv[rg] * acc[t][rg]);
        }
    }
}

// Layer-2 GEMM: C[M,64](bf16) = dinv[row]*(A[M,128](bf16) x Bt[64][128](bf16))
__global__ __launch_bounds__(256) void gemm2_kernel(const ushort* __restrict__ A,
        const ushort* __restrict__ Bt, ushort* __restrict__ C,
        const float* __restrict__ dinv, int M) {
    const int K = 128, N = 64;
    __shared__ __align__(16) ushort As[64][72];
    __shared__ __align__(16) ushort Bs[64][72];
    int tid = threadIdx.x;
    int bm = blockIdx.x * 64;
    int w = tid >> 6, lane = tid & 63;
    int m = lane & 15, quad = lane >> 4;
    f32x4 acc[4] = {};
    int r = tid >> 2, ks0 = (tid & 3) * 16;
    int grow = bm + r; if (grow >= M) grow = M - 1;
    const ushort* ap = A + (size_t)grow * K + ks0;
    const ushort* bp = Bt + (size_t)r * K + ks0;
    for (int k0 = 0; k0 < K; k0 += 64) {
        uint4 av0 = *(const uint4*)(ap + k0);
        uint4 av1 = *(const uint4*)(ap + k0 + 8);
        uint4 bv0 = *(const uint4*)(bp + k0);
        uint4 bv1 = *(const uint4*)(bp + k0 + 8);
        __syncthreads();
        *(uint4*)&As[r][ks0] = av0;
        *(uint4*)&As[r][ks0 + 8] = av1;
        *(uint4*)&Bs[r][ks0] = bv0;
        *(uint4*)&Bs[r][ks0 + 8] = bv1;
        __syncthreads();
        #pragma unroll
        for (int ks = 0; ks < 2; ++ks) {
            bf16x8 a = *(const bf16x8*)&As[w * 16 + m][ks * 32 + quad * 8];
            #pragma unroll
            for (int t = 0; t < 4; ++t) {
                bf16x8 b = *(const bf16x8*)&Bs[t * 16 + m][ks * 32 + quad * 8];
                acc[t] = __builtin_amdgcn_mfma_f32_16x16x32_bf16(a, b, acc[t], 0, 0, 0);
            }
        }
    }
    int rbase = bm + w * 16 + quad * 4;
    float dv[4];
    #pragma unroll
    for (int rg = 0; rg < 4; ++rg)
        dv[rg] = (rbase + rg < M) ? dinv[rbase + rg] : 0.0f;
    #pragma unroll
    for (int t = 0; t < 4; ++t) {
        int col = t * 16 + m;
        #pragma unroll
        for (int rg = 0; rg < 4; ++rg) {
            int row = rbase + rg;
            if (row < M)
                C[(size_t)row * N + col] = (ushort)f2bf(dv[rg] * acc[t][rg]);
        }
    }
}

// LPN lanes per node (F = LPN*8 bf16 features, 16 B per lane). H is pre-scaled
// by dinv[row]: out[n] = dinv[n]*(sum_j ew_j*H[s_j] + H[n]) + bias  (opt relu)
template<int F, int LPN, int RELU, int OUTBF>
__global__ __launch_bounds__(256) void agg_csr_kernel(
        const int* __restrict__ rowptr, const int2* __restrict__ edata,
        const ushort* __restrict__ H, const float* __restrict__ dinv,
        const float* __restrict__ bias, void* __restrict__ outv) {
    constexpr int NPB = 256 / LPN;
    int node = blockIdx.x * NPB + threadIdx.x / LPN;
    if (node >= NN) return;
    int glane = threadIdx.x & (LPN - 1);
    int gb = (threadIdx.x & 63) & ~(LPN - 1);     // group base lane within wave
    int beg = rowptr[node], end = rowptr[node + 1];
    float acc[8] = {};
    const ushort* Hl = H + (size_t)glane * 8;
    for (int chunk = beg; chunk < end; chunk += LPN) {
        int nch = end - chunk; if (nch > LPN) nch = LPN;
        int edx = 0, edy = 0;
        if (glane < nch) {
            int2 e = edata[chunk + glane];
            edx = e.x; edy = e.y;
        }
        int j = 0;
        for (; j + 2 <= nch; j += 2) {
            int s0 = __shfl(edx, gb + j);
            int s1 = __shfl(edx, gb + j + 1);
            float c0 = __int_as_float(__shfl(edy, gb + j));
            float c1 = __int_as_float(__shfl(edy, gb + j + 1));
            uint4 h0 = *(const uint4*)(Hl + (size_t)s0 * F);
            uint4 h1 = *(const uint4*)(Hl + (size_t)s1 * F);
            const unsigned* u0 = (const unsigned*)&h0;
            const unsigned* u1 = (const unsigned*)&h1;
            #pragma unroll
            for (int q = 0; q < 4; ++q) {
                acc[2*q]   += __uint_as_float(u0[q] << 16) * c0;
                acc[2*q+1] += __uint_as_float(u0[q] & 0xFFFF0000u) * c0;
            }
            #pragma unroll
            for (int q = 0; q < 4; ++q) {
                acc[2*q]   += __uint_as_float(u1[q] << 16) * c1;
                acc[2*q+1] += __uint_as_float(u1[q] & 0xFFFF0000u) * c1;
            }
        }
        if (j < nch) {
            int s0 = __shfl(edx, gb + j);
            float c0 = __int_as_float(__shfl(edy, gb + j));
            uint4 h0 = *(const uint4*)(Hl + (size_t)s0 * F);
            const unsigned* u0 = (const unsigned*)&h0;
            #pragma unroll
            for (int q = 0; q < 4; ++q) {
                acc[2*q]   += __uint_as_float(u0[q] << 16) * c0;
                acc[2*q+1] += __uint_as_float(u0[q] & 0xFFFF0000u) * c0;
            }
        }
    }
    float di = dinv[node];
    uint4 hn = *(const uint4*)(Hl + (size_t)node * F);
    const unsigned* un = (const unsigned*)&hn;
    float4 bv0 = *(const float4*)(bias + glane * 8);
    float4 bv1 = *(const float4*)(bias + glane * 8 + 4);
    float v[8];
    #pragma unroll
    for (int q = 0; q < 4; ++q) {
        v[2*q]   = di * (acc[2*q]   + __uint_as_float(un[q] << 16));
        v[2*q+1] = di * (acc[2*q+1] + __uint_as_float(un[q] & 0xFFFF0000u));
    }
    v[0] += bv0.x; v[1] += bv0.y; v[2] += bv0.z; v[3] += bv0.w;
    v[4] += bv1.x; v[5] += bv1.y; v[6] += bv1.z; v[7] += bv1.w;
    if (RELU) {
        #pragma unroll
        for (int k = 0; k < 8; ++k) v[k] = fmaxf(v[k], 0.0f);
    }
    if (OUTBF) {
        uint4 o;
        o.x = f2bf(v[0]) | (f2bf(v[1]) << 16);
        o.y = f2bf(v[2]) | (f2bf(v[3]) << 16);
        o.z = f2bf(v[4]) | (f2bf(v[5]) << 16);
        o.w = f2bf(v[6]) | (f2bf(v[7]) << 16);
        *(uint4*)((ushort*)outv + (size_t)node * F + glane * 8) = o;
    } else {
        float* o = (float*)outv + (size_t)node * F + glane * 8;
        *(float4*)(o)     = make_float4(v[0], v[1], v[2], v[3]);
        *(float4*)(o + 4) = make_float4(v[4], v[5], v[6], v[7]);
    }
}

extern "C" void kernel_launch(void* const* d_in, const int* in_sizes, int n_in,
                              void* d_out, int out_size, void* d_ws, size_t ws_size,
                              hipStream_t stream) {
    const float* x  = (const float*)d_in[0];
    const int*   ei = (const int*)d_in[1];
    const float* ew = (const float*)d_in[2];
    const float* W1 = (const float*)d_in[3];
    const float* b1 = (const float*)d_in[4];
    const float* W2 = (const float*)d_in[5];
    const float* b2 = (const float*)d_in[6];
    const int* src = ei;
    const int* dst = ei + NE;
    float* out = (float*)d_out;

    // workspace (dword offsets):
    float* ws     = (float*)d_ws;
    float* dinv   = ws;                        // 50048 dw
    int*   rowptr = (int*)(ws + 50048);        // 50064 dw (NN+1)
    int*   csum   = (int*)(ws + 100112);       // 50064 dw (NSEG+1)
    int*   bsum   = (int*)(ws + 150176);       // 352 dw
    int*   cntB   = (int*)(ws + 150528);       // 50048 dw
    ushort* Wt1   = (ushort*)(ws + 200576);    // 16384 dw
    ushort* Wt2   = Wt1 + 32768;               // 4096 dw -> ends 221056
    int2*  edata  = (int2*)(ws + 221056);      // 3.2M dw
    ushort* H1    = (ushort*)(ws + 3421056);   // [NN][128] bf16 row-major (H2 reuses)
    ushort* A1    = (ushort*)(ws + 6621056);   // [NN][128] bf16 row-major
    int2*  ebuf   = (int2*)A1;                 // aliases A1 (dead before agg1 writes)
    // total 9,821,056 dw = 39.3 MB

    // CSR build: zero global atomics (LDS counting sort, 2 levels)
    p1_hist<<<NBLK, 256, 0, stream>>>(dst, cntB);
    scan1_kernel<<<196, 256, 0, stream>>>(cntB, csum, bsum);
    scan2_kernel<<<1, 256, 0, stream>>>(bsum, csum);
    scan3_kernel<<<196, 256, 0, stream>>>(csum, bsum);
    wt_kernel<<<160, 256, 0, stream>>>(W1, W2, Wt1, Wt2);
    p3_scatter<<<NBLK, 256, 0, stream>>>(src, dst, ew, csum, ebuf);
    p4_build<<<NB, 256, 0, stream>>>(ebuf, csum, edata, dinv, rowptr);

    // Layer 1: H1'(bf16) = dinv*(x @ W1) -> agg -> A1(bf16, relu)
    gemm1_kernel<<<782, 256, 0, stream>>>(x, Wt1, H1, dinv, NN);
    agg_csr_kernel<128, 16, 1, 1><<<3125, 256, 0, stream>>>(rowptr, edata, H1, dinv, b1, A1);

    // Layer 2: H2'(bf16) = dinv*(A1 @ W2) (into H1 buffer) -> agg -> out(fp32)
    gemm2_kernel<<<782, 256, 0, stream>>>(A1, Wt2, H1, dinv, NN);
    agg_csr_kernel<64, 8, 0, 0><<<1563, 256, 0, stream>>>(rowptr, edata, H1, dinv, b2, out);
}